// Round 9
// baseline (344.384 us; speedup 1.0000x reference)
//
#include <hip/hip_runtime.h>
#include <hip/hip_bf16.h>

#define B_ 2
#define T_ 2048
#define C_ 1280
#define H_ 10
#define D_ 128
#define BT_ (B_*T_)

typedef __hip_bfloat16 bf16;
typedef __attribute__((ext_vector_type(8))) short short8;
typedef __attribute__((ext_vector_type(4))) float f32x4;

__device__ __forceinline__ float bf2f(bf16 v){ return __bfloat162float(v); }
__device__ __forceinline__ bf16  f2bf(float v){ return __float2bfloat16(v); }
__device__ __forceinline__ void stv(bf16* p, float v){ *p = f2bf(v); }
__device__ __forceinline__ void stv(float* p, float v){ *p = v; }

struct alignas(8) bf4 { bf16 a,b,c,d; };

__device__ __forceinline__ void gl2lds(const bf16* g, bf16* l) {
    __builtin_amdgcn_global_load_lds(
        (const __attribute__((address_space(1))) void*)g,
        (__attribute__((address_space(3))) void*)l,
        16, 0, 0);
}

// ---- fp32 -> bf16 bulk convert ----
__global__ __launch_bounds__(256)
void cvt(const float* __restrict__ s, bf16* __restrict__ d)
{
    const int i = (blockIdx.x*256 + threadIdx.x)*4;
    const float4 v = *(const float4*)(s + i);
    bf4 o = { f2bf(v.x), f2bf(v.y), f2bf(v.z), f2bf(v.w) };
    *(bf4*)(d + i) = o;
}

__global__ __launch_bounds__(256)
void cvtW(const float* __restrict__ s0, const float* __restrict__ s1,
          const float* __restrict__ s2, const float* __restrict__ s3,
          bf16* __restrict__ d)
{
    const int w = blockIdx.y;
    const float* s = (w==0)?s0:(w==1)?s1:(w==2)?s2:s3;
    const int i = (blockIdx.x*256 + threadIdx.x)*4;
    const float4 v = *(const float4*)(s + i);
    bf4 o = { f2bf(v.x), f2bf(v.y), f2bf(v.z), f2bf(v.w) };
    *(bf4*)(d + (size_t)w*C_*C_ + i) = o;
}

// ---- GEMM: O = A[4096,1280] @ W[1280,1280]^T, bf16 in, fp32 acc, BK=64 ----
template <typename OT>
__global__ __launch_bounds__(256,3)
void gemm_nt(const bf16* __restrict__ A, const bf16* __restrict__ Wb,
             OT* __restrict__ O0, OT* __restrict__ O1, OT* __restrict__ O2)
{
    __shared__ __align__(16) bf16 As[128*64];
    __shared__ __align__(16) bf16 Bs[128*64];
    const int z = blockIdx.z;
    const bf16* Wm = Wb + (size_t)z*C_*C_;
    OT*         Om = (z==0) ? O0 : (z==1) ? O1 : O2;
    const int wave = threadIdx.x >> 6;
    const int lane = threadIdx.x & 63;
    const int l15 = lane & 15, quad = lane >> 4;
    const int row0 = blockIdx.x*128;
    const int col0 = blockIdx.y*128;
    const int wm = (wave>>1)*64, wn = (wave&1)*64;
    const int srow = lane >> 3;
    const int scol = (lane & 7)*8;

    const f32x4 fzero = {0.f,0.f,0.f,0.f};
    f32x4 acc[4][4];
    #pragma unroll
    for (int i=0;i<4;i++)
        #pragma unroll
        for (int j=0;j<4;j++) acc[i][j] = fzero;

    const bf16* Ag = A  + (size_t)(row0 + wave*32 + srow)*C_ + scol;
    const bf16* Bg = Wm + (size_t)(col0 + wave*32 + srow)*C_ + scol;
    bf16* Al = As + (wave*32)*64;
    bf16* Bl = Bs + (wave*32)*64;

    for (int k0 = 0; k0 < C_; k0 += 64) {
        __syncthreads();
        #pragma unroll
        for (int i=0;i<4;i++){
            gl2lds(Ag + (size_t)i*8*C_ + k0, Al + i*8*64);
            gl2lds(Bg + (size_t)i*8*C_ + k0, Bl + i*8*64);
        }
        asm volatile("s_waitcnt vmcnt(0)" ::: "memory");
        __syncthreads();
        #pragma unroll
        for (int h=0; h<2; ++h) {
            short8 af[4], bfv[4];
            #pragma unroll
            for (int mt=0; mt<4; ++mt) af[mt]  = *(const short8*)(As + (wm + mt*16 + l15)*64 + h*32 + quad*8);
            #pragma unroll
            for (int nt=0; nt<4; ++nt) bfv[nt] = *(const short8*)(Bs + (wn + nt*16 + l15)*64 + h*32 + quad*8);
            #pragma unroll
            for (int mt=0; mt<4; ++mt)
                #pragma unroll
                for (int nt=0; nt<4; ++nt)
                    acc[mt][nt] = __builtin_amdgcn_mfma_f32_16x16x32_bf16(af[mt], bfv[nt], acc[mt][nt], 0,0,0);
        }
    }
    #pragma unroll
    for (int mt=0; mt<4; ++mt)
        #pragma unroll
        for (int nt=0; nt<4; ++nt)
            #pragma unroll
            for (int r=0; r<4; ++r)
                stv(&Om[(size_t)(row0 + wm + mt*16 + quad*4 + r)*C_ + col0 + wn + nt*16 + l15], acc[mt][nt][r]);
}

// ---- RoPE + RMS-norm, in place ----
__global__ __launch_bounds__(256)
void rope_rms(bf16* __restrict__ q, bf16* __restrict__ k,
              const float* __restrict__ cosp, const float* __restrict__ sinp)
{
    const int wave = threadIdx.x >> 6, lane = threadIdx.x & 63;
    const long rb = (long)blockIdx.x*4 + wave;
    const int h = (int)(rb % H_);
    const long bt = rb / H_;
    const int t = (int)(bt % T_);
    bf16* buf = blockIdx.y ? k : q;
    const size_t base = (size_t)bt*C_ + (size_t)h*D_;
    float x1 = bf2f(buf[base + lane]);
    float x2 = bf2f(buf[base + 64 + lane]);
    float c  = cosp[(size_t)t*64 + lane];
    float s  = sinp[(size_t)t*64 + lane];
    float y1 =  x1*c + x2*s;
    float y2 = -x1*s + x2*c;
    float ss = y1*y1 + y2*y2;
    #pragma unroll
    for (int off=1; off<64; off<<=1) ss += __shfl_xor(ss, off);
    float sc = rsqrtf(ss*(1.0f/128.0f) + 1e-5f);
    buf[base + lane]      = f2bf(y1*sc);
    buf[base + 64 + lane] = f2bf(y2*sc);
}

// ---- V transpose: Vt[bh][d][t] ----
__global__ __launch_bounds__(256)
void vtrans(const bf16* __restrict__ V, bf16* __restrict__ Vt)
{
    __shared__ float st[64][65];
    const int tid = threadIdx.x;
    const int bh = blockIdx.z;
    const int b = bh / H_, h = bh % H_;
    const int t0 = blockIdx.x*64, d0 = blockIdx.y*64;
    #pragma unroll
    for (int i=0;i<16;i++){
        int e = tid + i*256;
        int r = e >> 6, dd = e & 63;
        st[r][dd] = bf2f(V[(size_t)(b*T_ + t0 + r)*C_ + h*D_ + d0 + dd]);
    }
    __syncthreads();
    #pragma unroll
    for (int i=0;i<16;i++){
        int e = tid + i*256;
        int dd = e >> 6, r = e & 63;
        Vt[((size_t)bh*D_ + d0 + dd)*T_ + t0 + r] = f2bf(st[r][dd]);
    }
}

// ---- Flash attention v7: 64-row q-tile/block, 4 waves = 4 row-tiles, shared
// K chunks DMA'd to LDS (double-buffered, XOR-swizzled), V direct registers,
// fixed softmax max M0. Equal work: t<16 one block; t in [16,32) 2 half-range
// blocks + global combine. ----
#define M0_ 11.3137085f
__global__ __launch_bounds__(256,3)
void attn(const bf16* __restrict__ Q, const bf16* __restrict__ K,
          const bf16* __restrict__ Vt, bf16* __restrict__ Y,
          bf16* __restrict__ opart, float* __restrict__ lpart)
{
    __shared__ __align__(16) bf16 kbuf[2][64*128];   // [buf][key][16B-unit swizzle], 16 KB each
    __shared__ __align__(16) bf16 ptile[4][16*72];   // per-wave P tile
    const int wave = threadIdx.x >> 6, lane = threadIdx.x & 63;
    const int l15 = lane & 15, quad = lane >> 4;
    const int bid = blockIdx.x;
    const int bh = bid/48, u = bid%48;
    const bool split = (u < 32);                 // heavy blocks first
    const int t  = split ? (31 - (u>>1)) : (47 - u);
    const int s  = split ? (u & 1) : 0;
    const int b = bh / H_, h = bh % H_;
    const int t0 = t*64;
    const int nch = t + 1;                       // 64-key chunks
    const int cbeg = split ? (s*nch)>>1 : 0;
    const int cend = split ? ((s+1)*nch)>>1 : nch;
    const size_t base = (size_t)b*T_*C_ + (size_t)h*D_;
    const bf16* Kbh = K + base;
    const int t0w = t0 + wave*16;
    const float scale = 0.08838834764831845f;    // 1/sqrt(128)
    bf16* pt = ptile[wave];

    // Q fragments for this wave's 16 rows
    short8 qa[4];
    {
        const bf16* qp = Q + base + (size_t)(t0w + l15)*C_ + quad*8;
        #pragma unroll
        for (int kb4=0; kb4<4; ++kb4) qa[kb4] = *(const short8*)(qp + kb4*32);
    }
    const f32x4 fzero = {0.f,0.f,0.f,0.f};
    f32x4 o[8];
    #pragma unroll
    for (int dt=0; dt<8; ++dt) o[dt] = fzero;
    float lp[4] = {0.f,0.f,0.f,0.f};

    // DMA: wave w stages K rows [16w,16w+16) of chunk ch. Row-rotated 16B units:
    // LDS[key][u] holds global unit (u - key)&15  -> conflict-free frag reads.
    {   // prologue: first chunk into buf 0
        const int k0 = cbeg*64;
        #pragma unroll
        for (int j=0;j<4;j++){
            const int row = wave*16 + j*4 + quad;
            const int ug  = (l15 - row) & 15;
            gl2lds(Kbh + (size_t)(k0 + row)*C_ + ug*8, &kbuf[0][(wave*16 + j*4)*128]);
        }
    }

    for (int ch=cbeg; ch<cend; ++ch) {
        __syncthreads();                          // implicit vmcnt(0): chunk ch DMA done
        const int bsel = (ch - cbeg) & 1;
        if (ch+1 < cend) {
            const int k0n = (ch+1)*64;
            #pragma unroll
            for (int j=0;j<4;j++){
                const int row = wave*16 + j*4 + quad;
                const int ug  = (l15 - row) & 15;
                gl2lds(Kbh + (size_t)(k0n + row)*C_ + ug*8, &kbuf[bsel^1][(wave*16 + j*4)*128]);
            }
        }
        const int k0 = ch*64;
        const bf16* kb = &kbuf[bsel][0];
        // V loads: global -> registers, issued early, consumed after softmax
        short8 vf[16];
        const bf16* vp = Vt + ((size_t)bh*D_ + l15)*T_ + k0 + quad*8;
        #pragma unroll
        for (int dt=0; dt<8; ++dt) {
            vf[dt*2]   = *(const short8*)(vp + (size_t)dt*16*T_);
            vf[dt*2+1] = *(const short8*)(vp + (size_t)dt*16*T_ + 32);
        }
        // QK from LDS K
        f32x4 sc4[4];
        #pragma unroll
        for (int c=0;c<4;c++) sc4[c] = fzero;
        #pragma unroll
        for (int c=0;c<4;c++){
            short8 kf[4];
            #pragma unroll
            for (int kb4=0; kb4<4; ++kb4) {
                const int up = (kb4*4 + quad + l15) & 15;
                kf[kb4] = *(const short8*)(kb + (c*16 + l15)*128 + up*8);
            }
            #pragma unroll
            for (int kb4=0; kb4<4; ++kb4)
                sc4[c] = __builtin_amdgcn_mfma_f32_16x16x32_bf16(qa[kb4], kf[kb4], sc4[c], 0,0,0);
        }
        // softmax (fixed max) + P to LDS
        const bool lastc = (ch == nch-1);
        #pragma unroll
        for (int r=0; r<4; ++r) {
            const int rt = t0w + quad*4 + r;
            float v[4];
            #pragma unroll
            for (int c=0;c<4;c++) v[c] = sc4[c][r]*scale;
            if (lastc) {
                #pragma unroll
                for (int c=0;c<4;c++) if (k0 + c*16 + l15 > rt) v[c] = -1e30f;
            }
            float p[4];
            #pragma unroll
            for (int c=0;c<4;c++) p[c] = __expf(v[c] - M0_);
            lp[r] += (p[0]+p[1]) + (p[2]+p[3]);
            #pragma unroll
            for (int c=0;c<4;c++) pt[(quad*4+r)*72 + c*16 + l15] = f2bf(p[c]);
        }
        asm volatile("s_waitcnt lgkmcnt(0)" ::: "memory");   // own wave's P writes visible
        short8 pa[2];
        #pragma unroll
        for (int ks=0; ks<2; ++ks)
            pa[ks] = *(const short8*)(pt + l15*72 + ks*32 + quad*8);
        #pragma unroll
        for (int dt=0; dt<8; ++dt) {
            o[dt] = __builtin_amdgcn_mfma_f32_16x16x32_bf16(pa[0], vf[dt*2],   o[dt], 0,0,0);
            o[dt] = __builtin_amdgcn_mfma_f32_16x16x32_bf16(pa[1], vf[dt*2+1], o[dt], 0,0,0);
        }
    }

    // l reduction over the 16-lane row group
    #pragma unroll
    for (int r=0; r<4; ++r) {
        #pragma unroll
        for (int off=1; off<16; off<<=1) lp[r] += __shfl_xor(lp[r], off);
    }
    if (!split) {
        float li[4];
        #pragma unroll
        for (int r=0; r<4; ++r) li[r] = 1.0f/lp[r];
        #pragma unroll
        for (int dt=0; dt<8; ++dt)
            #pragma unroll
            for (int r=0; r<4; ++r)
                Y[base + (size_t)(t0w + quad*4 + r)*C_ + dt*16 + l15] = f2bf(o[dt][r]*li[r]);
    } else {
        const int slot = ((bh*16 + (t-16))<<1) | s;
        bf16* ob = opart + (size_t)slot*8192 + (wave*16)*128;
        #pragma unroll
        for (int dt=0; dt<8; ++dt)
            #pragma unroll
            for (int r=0; r<4; ++r)
                ob[(quad*4+r)*128 + dt*16 + l15] = f2bf(o[dt][r]);
        if (l15 == 0) {
            #pragma unroll
            for (int r=0; r<4; ++r) lpart[(size_t)slot*64 + wave*16 + quad*4 + r] = lp[r];
        }
    }
}

// ---- combine the 2 key-half partials for tiles t in [16,32) ----
__global__ __launch_bounds__(256)
void combine2(const bf16* __restrict__ opart, const float* __restrict__ lpart,
              bf16* __restrict__ Y)
{
    const int tt = blockIdx.x;            // 0..319: bh*16 + (t-16)
    const int bh = tt >> 4;
    const int t = 16 + (tt & 15);
    const int b = bh / H_, h = bh % H_;
    const int row = threadIdx.x >> 2;     // 0..63
    const int dseg = (threadIdx.x & 3)*32;
    const float li = 1.0f/(lpart[(size_t)(2*tt)*64 + row] + lpart[(size_t)(2*tt+1)*64 + row]);
    const bf16* p0 = opart + (size_t)(2*tt)*8192   + row*128 + dseg;
    const bf16* p1 = opart + (size_t)(2*tt+1)*8192 + row*128 + dseg;
    bf16 ov[32];
    #pragma unroll
    for (int e=0;e<32;e++) ov[e] = f2bf((bf2f(p0[e]) + bf2f(p1[e]))*li);
    bf16* yp = Y + (size_t)b*T_*C_ + (size_t)(t*64+row)*C_ + (size_t)h*D_ + dseg;
    #pragma unroll
    for (int v=0; v<4; ++v) *(short8*)(yp + v*8) = *(const short8*)(&ov[v*8]);
}

extern "C" void kernel_launch(void* const* d_in, const int* in_sizes, int n_in,
                              void* d_out, int out_size, void* d_ws, size_t ws_size,
                              hipStream_t stream)
{
    const float* x    = (const float*)d_in[0];
    const float* cosp = (const float*)d_in[1];
    const float* sinp = (const float*)d_in[2];
    const float* Wq   = (const float*)d_in[3];
    const float* Wk   = (const float*)d_in[4];
    const float* Wv   = (const float*)d_in[5];
    const float* Wp   = (const float*)d_in[6];
    float* out = (float*)d_out;

    const size_t NE = (size_t)BT_ * C_;
    const size_t NW = (size_t)C_ * C_;
    bf16* xb = (bf16*)d_ws;
    bf16* wb = xb + NE;
    bf16* q  = wb + 4*NW;
    bf16* k  = q + NE;
    bf16* v  = k + NE;
    bf16* y  = v + NE;
    bf16* vT = y + NE;
    bf16* op = vT + NE;                          // 640 slots x 8192 bf16 (10.5 MB)
    float* lpart = (float*)(op + (size_t)640*8192);   // 640 x 64 f32

    cvt<<<dim3(NE/1024), 256, 0, stream>>>(x, xb);
    cvtW<<<dim3(NW/1024, 4), 256, 0, stream>>>(Wq, Wk, Wv, Wp, wb);
    gemm_nt<bf16><<<dim3(BT_/128, C_/128, 3), 256, 0, stream>>>(xb, wb, q, k, v);
    rope_rms<<<dim3(BT_*H_/4, 2), 256, 0, stream>>>(q, k, cosp, sinp);
    vtrans<<<dim3(T_/64, D_/64, B_*H_), 256, 0, stream>>>(v, vT);
    attn<<<dim3(B_*H_*48), 256, 0, stream>>>(q, k, vT, y, op, lpart);
    combine2<<<dim3(320), 256, 0, stream>>>(op, lpart, y);
    gemm_nt<float><<<dim3(BT_/128, C_/128, 1), 256, 0, stream>>>(y, wb + 3*NW, out, out, out);
}

// Round 10
// 262.181 us; speedup vs baseline: 1.3135x; 1.3135x over previous
//
#include <hip/hip_runtime.h>
#include <hip/hip_bf16.h>

#define B_ 2
#define T_ 2048
#define C_ 1280
#define H_ 10
#define D_ 128
#define BT_ (B_*T_)

typedef __hip_bfloat16 bf16;
typedef __attribute__((ext_vector_type(8))) short short8;
typedef __attribute__((ext_vector_type(4))) float f32x4;

__device__ __forceinline__ float bf2f(bf16 v){ return __bfloat162float(v); }
__device__ __forceinline__ bf16  f2bf(float v){ return __float2bfloat16(v); }
__device__ __forceinline__ void stv(bf16* p, float v){ *p = f2bf(v); }
__device__ __forceinline__ void stv(float* p, float v){ *p = v; }

struct alignas(8) bf4 { bf16 a,b,c,d; };

__device__ __forceinline__ void gl2lds(const bf16* g, bf16* l) {
    __builtin_amdgcn_global_load_lds(
        (const __attribute__((address_space(1))) void*)g,
        (__attribute__((address_space(3))) void*)l,
        16, 0, 0);
}

// ---- fp32 -> bf16 bulk convert ----
__global__ __launch_bounds__(256)
void cvt(const float* __restrict__ s, bf16* __restrict__ d)
{
    const int i = (blockIdx.x*256 + threadIdx.x)*4;
    const float4 v = *(const float4*)(s + i);
    bf4 o = { f2bf(v.x), f2bf(v.y), f2bf(v.z), f2bf(v.w) };
    *(bf4*)(d + i) = o;
}

__global__ __launch_bounds__(256)
void cvtW(const float* __restrict__ s0, const float* __restrict__ s1,
          const float* __restrict__ s2, const float* __restrict__ s3,
          bf16* __restrict__ d)
{
    const int w = blockIdx.y;
    const float* s = (w==0)?s0:(w==1)?s1:(w==2)?s2:s3;
    const int i = (blockIdx.x*256 + threadIdx.x)*4;
    const float4 v = *(const float4*)(s + i);
    bf4 o = { f2bf(v.x), f2bf(v.y), f2bf(v.z), f2bf(v.w) };
    *(bf4*)(d + (size_t)w*C_*C_ + i) = o;
}

// ---- GEMM: O = A[4096,1280] @ W[1280,1280]^T, bf16 in, fp32 acc, BK=64 ----
template <typename OT>
__global__ __launch_bounds__(256,3)
void gemm_nt(const bf16* __restrict__ A, const bf16* __restrict__ Wb,
             OT* __restrict__ O0, OT* __restrict__ O1, OT* __restrict__ O2)
{
    __shared__ __align__(16) bf16 As[128*64];
    __shared__ __align__(16) bf16 Bs[128*64];
    const int z = blockIdx.z;
    const bf16* Wm = Wb + (size_t)z*C_*C_;
    OT*         Om = (z==0) ? O0 : (z==1) ? O1 : O2;
    const int wave = threadIdx.x >> 6;
    const int lane = threadIdx.x & 63;
    const int l15 = lane & 15, quad = lane >> 4;
    const int row0 = blockIdx.x*128;
    const int col0 = blockIdx.y*128;
    const int wm = (wave>>1)*64, wn = (wave&1)*64;
    const int srow = lane >> 3;
    const int scol = (lane & 7)*8;

    const f32x4 fzero = {0.f,0.f,0.f,0.f};
    f32x4 acc[4][4];
    #pragma unroll
    for (int i=0;i<4;i++)
        #pragma unroll
        for (int j=0;j<4;j++) acc[i][j] = fzero;

    const bf16* Ag = A  + (size_t)(row0 + wave*32 + srow)*C_ + scol;
    const bf16* Bg = Wm + (size_t)(col0 + wave*32 + srow)*C_ + scol;
    bf16* Al = As + (wave*32)*64;
    bf16* Bl = Bs + (wave*32)*64;

    for (int k0 = 0; k0 < C_; k0 += 64) {
        __syncthreads();
        #pragma unroll
        for (int i=0;i<4;i++){
            gl2lds(Ag + (size_t)i*8*C_ + k0, Al + i*8*64);
            gl2lds(Bg + (size_t)i*8*C_ + k0, Bl + i*8*64);
        }
        asm volatile("s_waitcnt vmcnt(0)" ::: "memory");
        __syncthreads();
        #pragma unroll
        for (int h=0; h<2; ++h) {
            short8 af[4], bfv[4];
            #pragma unroll
            for (int mt=0; mt<4; ++mt) af[mt]  = *(const short8*)(As + (wm + mt*16 + l15)*64 + h*32 + quad*8);
            #pragma unroll
            for (int nt=0; nt<4; ++nt) bfv[nt] = *(const short8*)(Bs + (wn + nt*16 + l15)*64 + h*32 + quad*8);
            #pragma unroll
            for (int mt=0; mt<4; ++mt)
                #pragma unroll
                for (int nt=0; nt<4; ++nt)
                    acc[mt][nt] = __builtin_amdgcn_mfma_f32_16x16x32_bf16(af[mt], bfv[nt], acc[mt][nt], 0,0,0);
        }
    }
    #pragma unroll
    for (int mt=0; mt<4; ++mt)
        #pragma unroll
        for (int nt=0; nt<4; ++nt)
            #pragma unroll
            for (int r=0; r<4; ++r)
                stv(&Om[(size_t)(row0 + wm + mt*16 + quad*4 + r)*C_ + col0 + wn + nt*16 + l15], acc[mt][nt][r]);
}

// ---- RoPE + RMS-norm, in place ----
__global__ __launch_bounds__(256)
void rope_rms(bf16* __restrict__ q, bf16* __restrict__ k,
              const float* __restrict__ cosp, const float* __restrict__ sinp)
{
    const int wave = threadIdx.x >> 6, lane = threadIdx.x & 63;
    const long rb = (long)blockIdx.x*4 + wave;
    const int h = (int)(rb % H_);
    const long bt = rb / H_;
    const int t = (int)(bt % T_);
    bf16* buf = blockIdx.y ? k : q;
    const size_t base = (size_t)bt*C_ + (size_t)h*D_;
    float x1 = bf2f(buf[base + lane]);
    float x2 = bf2f(buf[base + 64 + lane]);
    float c  = cosp[(size_t)t*64 + lane];
    float s  = sinp[(size_t)t*64 + lane];
    float y1 =  x1*c + x2*s;
    float y2 = -x1*s + x2*c;
    float ss = y1*y1 + y2*y2;
    #pragma unroll
    for (int off=1; off<64; off<<=1) ss += __shfl_xor(ss, off);
    float sc = rsqrtf(ss*(1.0f/128.0f) + 1e-5f);
    buf[base + lane]      = f2bf(y1*sc);
    buf[base + 64 + lane] = f2bf(y2*sc);
}

// ---- V transpose: Vt[bh][d][t] ----
__global__ __launch_bounds__(256)
void vtrans(const bf16* __restrict__ V, bf16* __restrict__ Vt)
{
    __shared__ float st[64][65];
    const int tid = threadIdx.x;
    const int bh = blockIdx.z;
    const int b = bh / H_, h = bh % H_;
    const int t0 = blockIdx.x*64, d0 = blockIdx.y*64;
    #pragma unroll
    for (int i=0;i<16;i++){
        int e = tid + i*256;
        int r = e >> 6, dd = e & 63;
        st[r][dd] = bf2f(V[(size_t)(b*T_ + t0 + r)*C_ + h*D_ + d0 + dd]);
    }
    __syncthreads();
    #pragma unroll
    for (int i=0;i<16;i++){
        int e = tid + i*256;
        int dd = e >> 6, r = e & 63;
        Vt[((size_t)bh*D_ + d0 + dd)*T_ + t0 + r] = f2bf(st[r][dd]);
    }
}

// ---- Flash attention v8: 64-row q-tile/block, 4 waves = 4 row-tiles.
// K AND V DMA-staged to LDS per 64-key chunk (single buffer, m97 2-barrier),
// row-rotation swizzles keep b128 reads at the bank floor. Fixed softmax max.
// Equal work: t<16 one block; t in [16,32) 2 half-range blocks + combine. ----
#define M0_ 11.3137085f
__global__ __launch_bounds__(256,3)
void attn(const bf16* __restrict__ Q, const bf16* __restrict__ K,
          const bf16* __restrict__ Vt, bf16* __restrict__ Y,
          bf16* __restrict__ opart, float* __restrict__ lpart)
{
    __shared__ __align__(16) bf16 kbuf[64*128];      // [key][16B-unit, rot16], 16 KB
    __shared__ __align__(16) bf16 vbuf[128*64];      // [d][16B-unit, rot8], 16 KB
    __shared__ __align__(16) bf16 ptile[4][16*72];   // per-wave P tile
    const int wave = threadIdx.x >> 6, lane = threadIdx.x & 63;
    const int l15 = lane & 15, quad = lane >> 4;
    const int bid = blockIdx.x;
    const int bh = bid/48, u = bid%48;
    const bool split = (u < 32);                 // heavy blocks first
    const int t  = split ? (31 - (u>>1)) : (47 - u);
    const int s  = split ? (u & 1) : 0;
    const int b = bh / H_, h = bh % H_;
    const int t0 = t*64;
    const int nch = t + 1;                       // 64-key chunks
    const int cbeg = split ? (s*nch)>>1 : 0;
    const int cend = split ? ((s+1)*nch)>>1 : nch;
    const size_t base = (size_t)b*T_*C_ + (size_t)h*D_;
    const bf16* Kbh = K + base;
    const bf16* Vbh = Vt + (size_t)bh*D_*T_;
    const int t0w = t0 + wave*16;
    const float scale = 0.08838834764831845f;    // 1/sqrt(128)
    bf16* pt = ptile[wave];

    short8 qa[4];
    {
        const bf16* qp = Q + base + (size_t)(t0w + l15)*C_ + quad*8;
        #pragma unroll
        for (int kb4=0; kb4<4; ++kb4) qa[kb4] = *(const short8*)(qp + kb4*32);
    }
    const f32x4 fzero = {0.f,0.f,0.f,0.f};
    f32x4 o[8];
    #pragma unroll
    for (int dt=0; dt<8; ++dt) o[dt] = fzero;
    float lp[4] = {0.f,0.f,0.f,0.f};

    // V DMA lane mapping (row stride 128 B = 8 units of 16 B)
    const int vr_off = lane >> 3;                // 0..7 within an 8-row group
    const int vu     = lane & 7;

    for (int ch=cbeg; ch<cend; ++ch) {
        const int k0 = ch*64;
        __syncthreads();                          // prev chunk's readers done
        // --- DMA K: wave stages key rows [16w,16w+16), rot-16 swizzle ---
        #pragma unroll
        for (int j=0;j<4;j++){
            const int row = wave*16 + j*4 + quad;
            const int ug  = (l15 - row) & 15;
            gl2lds(Kbh + (size_t)(k0 + row)*C_ + ug*8, &kbuf[(wave*16 + j*4)*128]);
        }
        // --- DMA V: wave stages d rows [32w,32w+32), rot-8 swizzle ---
        #pragma unroll
        for (int j=0;j<4;j++){
            const int r  = wave*32 + j*8 + vr_off;
            const int ug = (vu - r) & 7;
            gl2lds(Vbh + (size_t)r*T_ + k0 + ug*8, &vbuf[(wave*32 + j*8)*64]);
        }
        asm volatile("s_waitcnt vmcnt(0)" ::: "memory");
        __syncthreads();                          // staged chunk visible

        // --- QK from LDS K ---
        f32x4 sc4[4];
        #pragma unroll
        for (int c=0;c<4;c++) sc4[c] = fzero;
        #pragma unroll
        for (int c=0;c<4;c++){
            short8 kf[4];
            #pragma unroll
            for (int kb4=0; kb4<4; ++kb4) {
                const int up = (kb4*4 + quad + l15) & 15;
                kf[kb4] = *(const short8*)(&kbuf[(c*16 + l15)*128 + up*8]);
            }
            #pragma unroll
            for (int kb4=0; kb4<4; ++kb4)
                sc4[c] = __builtin_amdgcn_mfma_f32_16x16x32_bf16(qa[kb4], kf[kb4], sc4[c], 0,0,0);
        }
        // --- softmax (fixed max) + P to LDS ---
        const bool lastc = (ch == nch-1);
        #pragma unroll
        for (int r=0; r<4; ++r) {
            const int rt = t0w + quad*4 + r;
            float v[4];
            #pragma unroll
            for (int c=0;c<4;c++) v[c] = sc4[c][r]*scale;
            if (lastc) {
                #pragma unroll
                for (int c=0;c<4;c++) if (k0 + c*16 + l15 > rt) v[c] = -1e30f;
            }
            float p[4];
            #pragma unroll
            for (int c=0;c<4;c++) p[c] = __expf(v[c] - M0_);
            lp[r] += (p[0]+p[1]) + (p[2]+p[3]);
            #pragma unroll
            for (int c=0;c<4;c++) pt[(quad*4+r)*72 + c*16 + l15] = f2bf(p[c]);
        }
        asm volatile("s_waitcnt lgkmcnt(0)" ::: "memory");   // own wave's P writes visible
        short8 pa[2];
        #pragma unroll
        for (int ks=0; ks<2; ++ks)
            pa[ks] = *(const short8*)(pt + l15*72 + ks*32 + quad*8);
        // --- PV from LDS V ---
        #pragma unroll
        for (int dt=0; dt<8; ++dt) {
            #pragma unroll
            for (int ks=0; ks<2; ++ks) {
                const int up = (ks*4 + quad + l15) & 7;
                short8 vF = *(const short8*)(&vbuf[(dt*16 + l15)*64 + up*8]);
                o[dt] = __builtin_amdgcn_mfma_f32_16x16x32_bf16(pa[ks], vF, o[dt], 0,0,0);
            }
        }
    }

    // l reduction over the 16-lane row group
    #pragma unroll
    for (int r=0; r<4; ++r) {
        #pragma unroll
        for (int off=1; off<16; off<<=1) lp[r] += __shfl_xor(lp[r], off);
    }
    if (!split) {
        float li[4];
        #pragma unroll
        for (int r=0; r<4; ++r) li[r] = 1.0f/lp[r];
        #pragma unroll
        for (int dt=0; dt<8; ++dt)
            #pragma unroll
            for (int r=0; r<4; ++r)
                Y[base + (size_t)(t0w + quad*4 + r)*C_ + dt*16 + l15] = f2bf(o[dt][r]*li[r]);
    } else {
        const int slot = ((bh*16 + (t-16))<<1) | s;
        bf16* ob = opart + (size_t)slot*8192 + (wave*16)*128;
        #pragma unroll
        for (int dt=0; dt<8; ++dt)
            #pragma unroll
            for (int r=0; r<4; ++r)
                ob[(quad*4+r)*128 + dt*16 + l15] = f2bf(o[dt][r]);
        if (l15 == 0) {
            #pragma unroll
            for (int r=0; r<4; ++r) lpart[(size_t)slot*64 + wave*16 + quad*4 + r] = lp[r];
        }
    }
}

// ---- combine the 2 key-half partials for tiles t in [16,32) ----
__global__ __launch_bounds__(256)
void combine2(const bf16* __restrict__ opart, const float* __restrict__ lpart,
              bf16* __restrict__ Y)
{
    const int tt = blockIdx.x;            // 0..319: bh*16 + (t-16)
    const int bh = tt >> 4;
    const int t = 16 + (tt & 15);
    const int b = bh / H_, h = bh % H_;
    const int row = threadIdx.x >> 2;     // 0..63
    const int dseg = (threadIdx.x & 3)*32;
    const float li = 1.0f/(lpart[(size_t)(2*tt)*64 + row] + lpart[(size_t)(2*tt+1)*64 + row]);
    const bf16* p0 = opart + (size_t)(2*tt)*8192   + row*128 + dseg;
    const bf16* p1 = opart + (size_t)(2*tt+1)*8192 + row*128 + dseg;
    bf16 ov[32];
    #pragma unroll
    for (int e=0;e<32;e++) ov[e] = f2bf((bf2f(p0[e]) + bf2f(p1[e]))*li);
    bf16* yp = Y + (size_t)b*T_*C_ + (size_t)(t*64+row)*C_ + (size_t)h*D_ + dseg;
    #pragma unroll
    for (int v=0; v<4; ++v) *(short8*)(yp + v*8) = *(const short8*)(&ov[v*8]);
}

extern "C" void kernel_launch(void* const* d_in, const int* in_sizes, int n_in,
                              void* d_out, int out_size, void* d_ws, size_t ws_size,
                              hipStream_t stream)
{
    const float* x    = (const float*)d_in[0];
    const float* cosp = (const float*)d_in[1];
    const float* sinp = (const float*)d_in[2];
    const float* Wq   = (const float*)d_in[3];
    const float* Wk   = (const float*)d_in[4];
    const float* Wv   = (const float*)d_in[5];
    const float* Wp   = (const float*)d_in[6];
    float* out = (float*)d_out;

    const size_t NE = (size_t)BT_ * C_;
    const size_t NW = (size_t)C_ * C_;
    bf16* xb = (bf16*)d_ws;
    bf16* wb = xb + NE;
    bf16* q  = wb + 4*NW;
    bf16* k  = q + NE;
    bf16* v  = k + NE;
    bf16* y  = v + NE;
    bf16* vT = y + NE;
    bf16* op = vT + NE;                          // 640 slots x 8192 bf16 (10.5 MB)
    float* lpart = (float*)(op + (size_t)640*8192);   // 640 x 64 f32

    cvt<<<dim3(NE/1024), 256, 0, stream>>>(x, xb);
    cvtW<<<dim3(NW/1024, 4), 256, 0, stream>>>(Wq, Wk, Wv, Wp, wb);
    gemm_nt<bf16><<<dim3(BT_/128, C_/128, 3), 256, 0, stream>>>(xb, wb, q, k, v);
    rope_rms<<<dim3(BT_*H_/4, 2), 256, 0, stream>>>(q, k, cosp, sinp);
    vtrans<<<dim3(T_/64, D_/64, B_*H_), 256, 0, stream>>>(v, vT);
    attn<<<dim3(B_*H_*48), 256, 0, stream>>>(q, k, vT, y, op, lpart);
    combine2<<<dim3(320), 256, 0, stream>>>(op, lpart, y);
    gemm_nt<float><<<dim3(BT_/128, C_/128, 1), 256, 0, stream>>>(y, wb + 3*NW, out, out, out);
}